// Round 17
// baseline (179.941 us; speedup 1.0000x reference)
//
#include <hip/hip_runtime.h>
#include <hip/hip_bf16.h>

#define NN 768
#define MD 1024
#define NPAIR 295296            // 768*769/2
#define NPBLK2 2307             // NPAIR / 128 (exact, fallback kernel)

typedef __attribute__((ext_vector_type(8))) short s16x8;
typedef __attribute__((ext_vector_type(4))) float f32x4;
typedef __attribute__((ext_vector_type(2))) float f32x2;
typedef __attribute__((ext_vector_type(2))) __bf16 b16x2;

__device__ __forceinline__ ushort bf16_rn(float f) {
    uint u = __builtin_bit_cast(uint, f);
    u += 0x7FFFu + ((u >> 16) & 1u);
    return (ushort)(u >> 16);
}

// inverse triangular index (fallback kernel only)
__device__ __forceinline__ void ptoij(int p, int& io, int& jo) {
    const float disc = (float)(1537 * 1537 - 8 * p);
    int i = (int)((1537.0f - sqrtf(disc)) * 0.5f);
    i = i < 0 ? 0 : (i > 767 ? 767 : i);
    while (i > 0 && p < i * (1537 - i) / 2) --i;
    while (i < 767 && p >= (i + 1) * (1536 - i) / 2) ++i;
    io = i;
    jo = i + (p - i * (1537 - i) / 2);
}

#define GLOAD16(gsrc, ldst)                                                        \
    __builtin_amdgcn_global_load_lds(                                              \
        (const __attribute__((address_space(1))) void*)(gsrc),                     \
        (__attribute__((address_space(3))) void*)(ldst), 16, 0, 0)

// ---------- one-time: W2 -> bf16, FRAGMENT-major for register-direct loads -----
// frag f = ((c*2+ks)*8 + tn); WF[f*512 + lane*8 + e] = W2bf16[k][m]
// with k = tn*16 + (lane&15), m = c*64 + ks*32 + (lane>>4)*8 + e
__global__ __launch_bounds__(256) void w2frag(const float* __restrict__ W2,
                                              ushort* __restrict__ WF)
{
    const int id = blockIdx.x * 256 + threadIdx.x;   // 0..16383
    const int lane = id & 63;
    const int f = id >> 6;          // 0..255
    const int tn = f & 7;
    const int ks = (f >> 3) & 1;
    const int c  = f >> 4;
    const int k = tn * 16 + (lane & 15);
    const int m = c * 64 + ks * 32 + (lane >> 4) * 8;
    const float4 a = *reinterpret_cast<const float4*>(W2 + k * MD + m);
    const float4 b = *reinterpret_cast<const float4*>(W2 + k * MD + m + 4);
    const float w[8] = {a.x, a.y, a.z, a.w, b.x, b.y, b.z, b.w};
    s16x8 h;
#pragma unroll
    for (int e = 0; e < 8; ++e) h[e] = (short)bf16_rn(w[e]);
    *reinterpret_cast<s16x8*>(WF + id * 8) = h;
}

// ---------- one-time: EA rows (f32) : EA[i][m] = 2^(-(a_m x_i + b_m) log2e) ----
__global__ __launch_bounds__(256) void eaprep(const float* __restrict__ x,
                                              const float* __restrict__ W1,
                                              const float* __restrict__ b1,
                                              float* __restrict__ EAg)
{
    const int i = blockIdx.x;
    const float xi = x[i];
    const float NL2E = -1.4426950408889634f;
    for (int m = threadIdx.x; m < MD; m += 256) {
        const float2 w = reinterpret_cast<const float2*>(W1)[m];
        EAg[i * MD + m] = __builtin_amdgcn_exp2f(fmaf(w.x, xi, b1[m]) * NL2E);
    }
}

// ---------- one-time: EC factors bf16 in MFMA-FRAGMENT order -------------------
// ECF[jg][c][ks][lane*8+e] with lane = l4*16 + (j&15), j = jg*16 + (j&15),
// m = c*64 + ks*32 + l4*8 + e ; value = bf16(2^(-c_m x_j log2e))
__global__ __launch_bounds__(256) void ecfprep(const float* __restrict__ x,
                                               const float* __restrict__ W1,
                                               ushort* __restrict__ ECF)
{
    const int id = blockIdx.x * 256 + threadIdx.x;   // 0..98303 (768 j x 128 m8)
    const int j = id >> 7;
    const int m8 = id & 127;
    const float xj = x[j];
    const float NL2E = -1.4426950408889634f;
    const int mbase = m8 * 8;
    s16x8 h;
#pragma unroll
    for (int e = 0; e < 8; ++e) {
        const float cm = W1[(mbase + e) * 2 + 1];
        h[e] = (short)bf16_rn(__builtin_amdgcn_exp2f(cm * xj * NL2E));
    }
    const int c    = mbase >> 6;
    const int ks   = (mbase >> 5) & 1;
    const int l4   = (mbase & 31) >> 3;
    const int lane = l4 * 16 + (j & 15);
    const int off  = (j >> 4) * 16384 + c * 1024 + ks * 512 + lane * 8;
    *reinterpret_cast<s16x8*>(ECF + off) = h;
}

// ---- table-kernel macros (ambient locals) --------------------------------------
#define LOADB_T(cc, ks)                                                      \
    {                                                                        \
        const ushort* wb_ = WF + (cc) * 8192 + (ks) * 4096 + lane * 8;       \
        _Pragma("unroll")                                                    \
        for (int tn_ = 0; tn_ < 8; ++tn_)                                    \
            bh[tn_] = *reinterpret_cast<const s16x8*>(wb_ + tn_ * 512);      \
    }

#define LOADEC(cc, ks, dst)                                                  \
    {                                                                        \
        const ushort* e_ = ECF + jg0 * 16384 + (cc) * 1024 + (ks) * 512 + lane * 8; \
        dst[0] = *reinterpret_cast<const s16x8*>(e_);                        \
        dst[1] = *reinterpret_cast<const s16x8*>(e_ + 16384);                \
    }

// sigma = rcp(1 + EA*EC): 1 transcendental per value (no exp2 in hot loop)
#define SIG_T(cc, ks_, ec)                                                   \
    {                                                                        \
        const int m0_ = (cc) * 64 + (ks_) * 32 + l4 * 8;                     \
        const f32x4 ea0_ = *reinterpret_cast<const f32x4*>(&EAl[m0_]);       \
        const f32x4 ea1_ = *reinterpret_cast<const f32x4*>(&EAl[m0_ + 4]);   \
        _Pragma("unroll")                                                    \
        for (int tm_ = 0; tm_ < 2; ++tm_) {                                  \
            union { s16x8 v; uint u[4]; } ec_;                               \
            ec_.v = ec[tm_];                                                 \
            union { s16x8 v; uint u[4]; } fr_;                               \
            _Pragma("unroll")                                                \
            for (int h_ = 0; h_ < 4; ++h_) {                                 \
                const uint uu_ = ec_.u[h_];                                  \
                const float el_ = __builtin_bit_cast(float, uu_ << 16);      \
                const float eh_ = __builtin_bit_cast(float, uu_ & 0xFFFF0000u); \
                const float ga_ = (h_ < 2) ? ea0_[2 * h_] : ea1_[2 * h_ - 4];     \
                const float gb_ = (h_ < 2) ? ea0_[2 * h_ + 1] : ea1_[2 * h_ - 3]; \
                const float t0_ = fmaf(el_, ga_, 1.0f);                      \
                const float t1_ = fmaf(eh_, gb_, 1.0f);                      \
                b16x2 p_;                                                    \
                p_.x = (__bf16)__builtin_amdgcn_rcpf(t0_);                   \
                p_.y = (__bf16)__builtin_amdgcn_rcpf(t1_);                   \
                fr_.u[h_] = __builtin_bit_cast(uint, p_);                    \
            }                                                                \
            ah[tm_] = fr_.v;                                                 \
        }                                                                    \
    }

#define MFMA_T()                                                             \
    {                                                                        \
        __builtin_amdgcn_s_setprio(1);                                       \
        _Pragma("unroll")                                                    \
        for (int tm_ = 0; tm_ < 2; ++tm_)                                    \
            _Pragma("unroll")                                                \
            for (int tn_ = 0; tn_ < 8; ++tn_)                                \
                acc[tm_][tn_] = __builtin_amdgcn_mfma_f32_16x16x32_bf16(     \
                    ah[tm_], bh[tn_], acc[tm_][tn_], 0, 0, 0);               \
        __builtin_amdgcn_s_setprio(0);                                       \
    }

// ---------- main: row-block (i, 128 j), tables, register-direct, zero barriers -
__global__ __launch_bounds__(256, 3) void mlp_tab(
    const float* __restrict__ EAg, const ushort* __restrict__ ECF,
    const ushort* __restrict__ WF,
    const float* __restrict__ b2, const float* __restrict__ W3,
    const float* __restrict__ b3, float* __restrict__ K)
{
    const int i  = blockIdx.y;
    const int j0 = blockIdx.x * 128;
    if (j0 + 127 < i) return;                 // fully below diagonal

    __shared__ __align__(16) float EAl[MD];   // 4 KB only

    const int t = threadIdx.x;
    const int lane = t & 63, wv = t >> 6;
    const int l15 = lane & 15, l4 = lane >> 4;

    const int jw  = j0 + wv * 32;             // wave's 32 j rows
    const int jg0 = jw >> 4;                  // first of two 16-j fragment groups

    // prologue: stage EA row (4KB) + first W2/EC frag loads
    GLOAD16(EAg + i * MD + wv * 256 + lane * 4, (char*)EAl + wv * 1024);

    f32x4 acc[2][8];
#pragma unroll
    for (int a = 0; a < 2; ++a)
#pragma unroll
        for (int b = 0; b < 8; ++b) acc[a][b] = (f32x4){0.f, 0.f, 0.f, 0.f};

    s16x8 bh[8], ecA[2], ecB[2], ah[2];
    LOADB_T(0, 0);
    LOADEC(0, 0, ecA);
    __syncthreads();                 // EAl resident (the ONLY barrier)

    for (int c = 0; c < 16; ++c) {
        LOADEC(c, 1, ecB);           // flies over SIG0+MFMA0
        SIG_T(c, 0, ecA);            // consumes ecA; covers in-flight bh ks0
        MFMA_T();                    // consumes bh = ks0
        LOADB_T(c, 1);               // refill bh with ks1 frags
        if (c < 15) LOADEC(c + 1, 0, ecA);   // flies over SIG1+MFMA1
        SIG_T(c, 1, ecB);
        MFMA_T();                    // consumes bh = ks1
        if (c < 15) LOADB_T(c + 1, 0);
    }

    // epilogue: v = sum_k W3[k]*relu(h2 + b2[k]) + b3; reduce over 16 lanes (k)
    float w3v[8], b2v[8];
#pragma unroll
    for (int tn = 0; tn < 8; ++tn) {
        const int k = tn * 16 + l15;
        w3v[tn] = W3[k];
        b2v[tn] = b2[k];
    }
    const float b3v = b3[0];
#pragma unroll
    for (int tm = 0; tm < 2; ++tm)
#pragma unroll
        for (int r = 0; r < 4; ++r) {
            float v = 0.f;
#pragma unroll
            for (int tn = 0; tn < 8; ++tn)
                v = fmaf(w3v[tn], fmaxf(acc[tm][tn][r] + b2v[tn], 0.f), v);
            v += __shfl_xor(v, 1, 16);
            v += __shfl_xor(v, 2, 16);
            v += __shfl_xor(v, 4, 16);
            v += __shfl_xor(v, 8, 16);
            if (l15 == 0) {
                const int j = jw + tm * 16 + l4 * 4 + r;
                if (j >= i) K[i * NN + j] = v + b3v;
            }
        }
}

// ---------- fallback (R16 proven): pair-flattened, exp2-in-loop, zero barriers -
#define LOADB(cc, ks)                                                        \
    {                                                                        \
        const ushort* wb_ = WF + (cc) * 8192 + (ks) * 4096 + lane * 8;       \
        _Pragma("unroll")                                                    \
        for (int tn_ = 0; tn_ < 8; ++tn_)                                    \
            bh[tn_] = *reinterpret_cast<const s16x8*>(wb_ + tn_ * 512);      \
    }

#define SIG_HALF(cc, ks_)                                                    \
    {                                                                        \
        const int m0_ = (cc) * 64 + (ks_) * 32 + l4 * 8;                     \
        const f32x4 a0_ = *reinterpret_cast<const f32x4*>(&sa[m0_]);         \
        const f32x4 a1_ = *reinterpret_cast<const f32x4*>(&sa[m0_ + 4]);     \
        const f32x4 c0_ = *reinterpret_cast<const f32x4*>(&sc[m0_]);         \
        const f32x4 c1_ = *reinterpret_cast<const f32x4*>(&sc[m0_ + 4]);     \
        const f32x4 b0_ = *reinterpret_cast<const f32x4*>(&sb[m0_]);         \
        const f32x4 b1_ = *reinterpret_cast<const f32x4*>(&sb[m0_ + 4]);     \
        _Pragma("unroll")                                                    \
        for (int tm_ = 0; tm_ < 2; ++tm_) {                                  \
            const f32x2 xi2_ = (f32x2){xia[tm_], xia[tm_]};                  \
            const f32x2 xj2_ = (f32x2){xja[tm_], xja[tm_]};                  \
            const f32x2 one2_ = (f32x2){1.f, 1.f};                           \
            union { s16x8 v; uint u[4]; } fr_;                               \
            _Pragma("unroll")                                                \
            for (int h_ = 0; h_ < 4; ++h_) {                                 \
                f32x2 av_, cv_, bv_;                                         \
                if (h_ < 2) {                                                \
                    av_ = (f32x2){a0_[2 * h_], a0_[2 * h_ + 1]};             \
                    cv_ = (f32x2){c0_[2 * h_], c0_[2 * h_ + 1]};             \
                    bv_ = (f32x2){b0_[2 * h_], b0_[2 * h_ + 1]};             \
                } else {                                                     \
                    av_ = (f32x2){a1_[2 * h_ - 4], a1_[2 * h_ - 3]};         \
                    cv_ = (f32x2){c1_[2 * h_ - 4], c1_[2 * h_ - 3]};         \
                    bv_ = (f32x2){b1_[2 * h_ - 4], b1_[2 * h_ - 3]};         \
                }                                                            \
                const f32x2 u2_ = __builtin_elementwise_fma(                 \
                    xi2_, av_, __builtin_elementwise_fma(xj2_, cv_, bv_));   \
                f32x2 e2_;                                                   \
                e2_[0] = __builtin_amdgcn_exp2f(u2_[0]);                     \
                e2_[1] = __builtin_amdgcn_exp2f(u2_[1]);                     \
                const f32x2 t2_ = e2_ + one2_;                               \
                b16x2 p_;                                                    \
                p_.x = (__bf16)__builtin_amdgcn_rcpf(t2_[0]);                \
                p_.y = (__bf16)__builtin_amdgcn_rcpf(t2_[1]);                \
                fr_.u[h_] = __builtin_bit_cast(uint, p_);                    \
            }                                                                \
            ah[tm_] = fr_.v;                                                 \
        }                                                                    \
    }

#define MFMA_HALF()                                                          \
    {                                                                        \
        __builtin_amdgcn_s_setprio(1);                                       \
        _Pragma("unroll")                                                    \
        for (int tm_ = 0; tm_ < 2; ++tm_)                                    \
            _Pragma("unroll")                                                \
            for (int tn_ = 0; tn_ < 8; ++tn_)                                \
                acc[tm_][tn_] = __builtin_amdgcn_mfma_f32_16x16x32_bf16(     \
                    ah[tm_], bh[tn_], acc[tm_][tn_], 0, 0, 0);               \
        __builtin_amdgcn_s_setprio(0);                                       \
    }

__global__ __launch_bounds__(256, 3) void mlp_pairs_reg(
    const float* __restrict__ x,
    const float* __restrict__ W1, const float* __restrict__ b1,
    const ushort* __restrict__ WF,
    const float* __restrict__ b2, const float* __restrict__ W3,
    const float* __restrict__ b3, float* __restrict__ K)
{
    __shared__ __align__(16) float sa[MD], sc[MD], sb[MD];

    const int t = threadIdx.x;
    const int lane = t & 63;
    const int l15 = lane & 15, l4 = lane >> 4;
    const int wv = t >> 6;

    const float NL2E = -1.4426950408889634f;
    for (int m = t; m < MD; m += 256) {
        const float2 w = reinterpret_cast<const float2*>(W1)[m];
        sa[m] = w.x * NL2E;
        sc[m] = w.y * NL2E;
        sb[m] = b1[m] * NL2E;
    }

    const int pairbase = blockIdx.x * 128 + wv * 32;

    float xia[2], xja[2];
#pragma unroll
    for (int tm = 0; tm < 2; ++tm) {
        const int p = pairbase + tm * 16 + l15;
        if (p < NPAIR) {
            int i, j;
            ptoij(p, i, j);
            xia[tm] = x[i];
            xja[tm] = x[j];
        } else {
            xia[tm] = 0.f;
            xja[tm] = 0.f;
        }
    }

    f32x4 acc[2][8];
#pragma unroll
    for (int a = 0; a < 2; ++a)
#pragma unroll
        for (int b = 0; b < 8; ++b) acc[a][b] = (f32x4){0.f, 0.f, 0.f, 0.f};

    s16x8 bh[8];
    LOADB(0, 0);
    __syncthreads();

    s16x8 ah[2];
    for (int c = 0; c < 16; ++c) {
        SIG_HALF(c, 0);
        MFMA_HALF();
        LOADB(c, 1);
        SIG_HALF(c, 1);
        MFMA_HALF();
        if (c < 15) LOADB(c + 1, 0);
    }

    float w3v[8], b2v[8];
#pragma unroll
    for (int tn = 0; tn < 8; ++tn) {
        const int k = tn * 16 + l15;
        w3v[tn] = W3[k];
        b2v[tn] = b2[k];
    }
    const float b3v = b3[0];
#pragma unroll
    for (int tm = 0; tm < 2; ++tm)
#pragma unroll
        for (int r = 0; r < 4; ++r) {
            float v = 0.f;
#pragma unroll
            for (int tn = 0; tn < 8; ++tn)
                v = fmaf(w3v[tn], fmaxf(acc[tm][tn][r] + b2v[tn], 0.f), v);
            v += __shfl_xor(v, 1, 16);
            v += __shfl_xor(v, 2, 16);
            v += __shfl_xor(v, 4, 16);
            v += __shfl_xor(v, 8, 16);
            if (l15 == 0) {
                const int p = pairbase + tm * 16 + l4 * 4 + r;
                if (p < NPAIR) {
                    int i, j;
                    ptoij(p, i, j);
                    K[i * NN + j] = v + b3v;
                }
            }
        }
}

// ---------- Kernel 2: C = K^T K, symmetric — compute upper tiles, mirror -------
__global__ __launch_bounds__(256) void ktk(const float* __restrict__ K,
                                           float* __restrict__ C)
{
    const int b0 = blockIdx.x * 64;
    const int a0 = blockIdx.y * 64;
    if (b0 < a0) return;             // C symmetric: only tiles with b0 >= a0
    __shared__ float Ka[64][68];
    __shared__ float Kb[64][68];
    const int t  = threadIdx.x;
    const int tb = t & 15;
    const int ta = t >> 4;
    float acc[4][4];
#pragma unroll
    for (int u = 0; u < 4; u++)
#pragma unroll
        for (int v = 0; v < 4; v++) acc[u][v] = 0.f;
    const int kmax = a0 + 64;        // K[k][a]=0 for k>a; a0 <= b0
    for (int k0 = 0; k0 < kmax; k0 += 64) {
#pragma unroll
        for (int q = 0; q < 4; q++) {
            const int f  = t + q * 256;
            const int kk = f >> 4;
            const int c4 = (f & 15) * 4;
            *reinterpret_cast<float4*>(&Ka[kk][c4]) =
                *reinterpret_cast<const float4*>(K + (k0 + kk) * NN + a0 + c4);
            *reinterpret_cast<float4*>(&Kb[kk][c4]) =
                *reinterpret_cast<const float4*>(K + (k0 + kk) * NN + b0 + c4);
        }
        __syncthreads();
#pragma unroll 8
        for (int kk = 0; kk < 64; kk++) {
            const float4 av = *reinterpret_cast<const float4*>(&Ka[kk][ta * 4]);
            const float4 bv = *reinterpret_cast<const float4*>(&Kb[kk][tb * 4]);
            const float a4[4] = {av.x, av.y, av.z, av.w};
            const float b4[4] = {bv.x, bv.y, bv.z, bv.w};
#pragma unroll
            for (int u = 0; u < 4; u++)
#pragma unroll
                for (int v = 0; v < 4; v++)
                    acc[u][v] = fmaf(a4[u], b4[v], acc[u][v]);
        }
        __syncthreads();
    }
#pragma unroll
    for (int u = 0; u < 4; u++) {
        float4 o;
        o.x = acc[u][0]; o.y = acc[u][1]; o.z = acc[u][2]; o.w = acc[u][3];
        *reinterpret_cast<float4*>(C + (a0 + ta * 4 + u) * NN + b0 + tb * 4) = o;
    }
    if (b0 > a0) {                   // mirror tile: C[b][a] = C[a][b], coalesced
#pragma unroll
        for (int v = 0; v < 4; v++) {
            float4 o;
            o.x = acc[0][v]; o.y = acc[1][v]; o.z = acc[2][v]; o.w = acc[3][v];
            *reinterpret_cast<float4*>(C + (b0 + tb * 4 + v) * NN + a0 + ta * 4) = o;
        }
    }
}

extern "C" void kernel_launch(void* const* d_in, const int* in_sizes, int n_in,
                              void* d_out, int out_size, void* d_ws, size_t ws_size,
                              hipStream_t stream)
{
    const float* x  = (const float*)d_in[0];
    const float* W1 = (const float*)d_in[1];
    const float* b1 = (const float*)d_in[2];
    const float* W2 = (const float*)d_in[3];
    const float* b2 = (const float*)d_in[4];
    const float* W3 = (const float*)d_in[5];
    const float* b3 = (const float*)d_in[6];
    float* Kmat = (float*)d_ws;                       // 2,359,296 B
    float* C    = (float*)d_out;

    const size_t kBytes  = (size_t)NN * NN * sizeof(float);
    const size_t wBytes  = 262144;                            // WF bf16 frag-major
    const size_t eaB     = (size_t)NN * MD * sizeof(float);   // 3 MB
    const size_t ecB     = (size_t)48 * 16384 * sizeof(ushort); // 1.5 MB
    const size_t needTab = kBytes + wBytes + eaB + ecB;       // ~7.2 MB
    const size_t needFB  = kBytes + wBytes;

    hipMemsetAsync(Kmat, 0, kBytes, stream);
    if (ws_size >= needTab) {
        ushort* WF  = (ushort*)((char*)d_ws + kBytes);
        float*  EAg = (float*)((char*)d_ws + kBytes + wBytes);
        ushort* ECF = (ushort*)((char*)d_ws + kBytes + wBytes + eaB);
        w2frag<<<64, 256, 0, stream>>>(W2, WF);
        eaprep<<<NN, 256, 0, stream>>>(x, W1, b1, EAg);
        ecfprep<<<384, 256, 0, stream>>>(x, W1, ECF);
        mlp_tab<<<dim3(6, NN), 256, 0, stream>>>(EAg, ECF, WF, b2, W3, b3, Kmat);
    } else if (ws_size >= needFB) {
        ushort* WF = (ushort*)((char*)d_ws + kBytes);
        w2frag<<<64, 256, 0, stream>>>(W2, WF);
        mlp_pairs_reg<<<NPBLK2, 256, 0, stream>>>(x, W1, b1, WF, b2, W3, b3, Kmat);
    }
    ktk<<<dim3(NN / 64, NN / 64), 256, 0, stream>>>(Kmat, C);
}